// Round 1
// baseline (343.018 us; speedup 1.0000x reference)
//
#include <hip/hip_runtime.h>

// Fastfood transform, MI355X/gfx950.
// out[b, s*1024 + i] = S[s,i] * FWHT1024( G∘ gather_P( FWHT1024( B[s,:]∘x[b,:] ) ) )[i] + bias
// Layout: block = 256 thr = 4 waves; wave w = stack w; lane holds 16 elems of the
// 1024-transform at i = q*256 + lane*4 + r  (q,r = reg bits -> i-bits {8,9} and {0,1}).
// In-lane FWHT16 covers i-bits {0,1,8,9}; cross-lane stages = lane-xor {1,2,4,8,16,32}:
//   1,2 -> DPP quad_perm ; 8 -> DPP row_ror:8 ; 4 -> ds_swizzle ; 16,32 -> v_permlane*_swap pair trick.

constexpr int BATCH_N  = 16384;
constexpr int NIN      = 1024;   // IN_EXT
constexpr int NOUT     = 4096;   // NSTACK * IN_EXT
constexpr int ROWS_PB  = 16;     // rows per block
constexpr int NBLOCKS  = BATCH_N / ROWS_PB;  // 1024

template <int CTRL>
__device__ __forceinline__ float dpp_mov_f(float v) {
    return __int_as_float(__builtin_amdgcn_update_dpp(
        0, __float_as_int(v), CTRL, 0xF, 0xF, true));
}

__device__ __forceinline__ float swz_xor4(float v) {
    // ds_swizzle BitMode: offset = (xor<<10)|(or<<5)|and = (4<<10)|31 = 0x101F -> lane^4
    return __int_as_float(__builtin_amdgcn_ds_swizzle(__float_as_int(v), 0x101F));
}

__device__ __forceinline__ void bf_sel(float& v, float p, bool hi) {
    // butterfly: lanes with bit clear -> a+b ; bit set -> (partner - self)
    v = hi ? (p - v) : (v + p);
}

__device__ __forceinline__ void bf_pl16(float& a, float& b) {
    // xor16 butterfly on two regs via v_permlane16_swap pair trick (VALU pipe)
    asm("v_permlane16_swap_b32 %0, %1" : "+v"(a), "+v"(b));
    float s = a + b;
    float d = a - b;
    asm("v_permlane16_swap_b32 %0, %1" : "+v"(s), "+v"(d));
    a = s; b = d;
}

__device__ __forceinline__ void bf_pl32(float& a, float& b) {
    asm("v_permlane32_swap_b32 %0, %1" : "+v"(a), "+v"(b));
    float s = a + b;
    float d = a - b;
    asm("v_permlane32_swap_b32 %0, %1" : "+v"(s), "+v"(d));
    a = s; b = d;
}

__device__ __forceinline__ void fwht1024(float y[16], int lane) {
    // in-register stages: i-bits {0,1,8,9} == t-bits {0,1,2,3}
    #pragma unroll
    for (int h = 1; h < 16; h <<= 1) {
        #pragma unroll
        for (int t = 0; t < 16; t++) {
            if (!(t & h)) {
                float a = y[t], b = y[t ^ h];
                y[t]     = a + b;
                y[t ^ h] = a - b;
            }
        }
    }
    const bool b1 = (lane & 1) != 0;
    const bool b2 = (lane & 2) != 0;
    const bool b4 = (lane & 4) != 0;
    const bool b8 = (lane & 8) != 0;
    #pragma unroll
    for (int t = 0; t < 16; t++) bf_sel(y[t], dpp_mov_f<0xB1>(y[t]), b1);  // quad_perm [1,0,3,2]
    #pragma unroll
    for (int t = 0; t < 16; t++) bf_sel(y[t], dpp_mov_f<0x4E>(y[t]), b2);  // quad_perm [2,3,0,1]
    #pragma unroll
    for (int t = 0; t < 16; t++) bf_sel(y[t], swz_xor4(y[t]), b4);         // lane^4
    #pragma unroll
    for (int t = 0; t < 16; t++) bf_sel(y[t], dpp_mov_f<0x128>(y[t]), b8); // row_ror:8 == lane^8
    #pragma unroll
    for (int t = 0; t < 16; t += 2) bf_pl16(y[t], y[t + 1]);               // lane^16
    #pragma unroll
    for (int t = 0; t < 16; t += 2) bf_pl32(y[t], y[t + 1]);               // lane^32
}

__global__ __launch_bounds__(256, 3)
void fastfood_kernel(const float* __restrict__ x,  const float* __restrict__ Bm,
                     const float* __restrict__ Gm, const float* __restrict__ Sm,
                     const float* __restrict__ bias, const int* __restrict__ Pm,
                     float* __restrict__ out)
{
    __shared__ float zbuf[NOUT];  // full 4096-wide intermediate, standard index order

    const int tid  = threadIdx.x;
    const int w    = tid >> 6;        // wave id == stack id
    const int lane = tid & 63;
    const int col  = lane << 2;       // 4-float chunk within a 256 block
    const int pb   = w * NIN + col;   // param base; + q*256

    // ---- load per-stack params into registers once per block (amortized over 16 rows)
    float Br[16], Gr[16], Sr[16], Ar[16];
    int   Pr[16];
    #pragma unroll
    for (int q = 0; q < 4; q++) {
        float4 t;
        t = *(const float4*)(Bm + pb + q * 256);
        Br[q*4+0] = t.x; Br[q*4+1] = t.y; Br[q*4+2] = t.z; Br[q*4+3] = t.w;
        t = *(const float4*)(Gm + pb + q * 256);
        Gr[q*4+0] = t.x; Gr[q*4+1] = t.y; Gr[q*4+2] = t.z; Gr[q*4+3] = t.w;
        t = *(const float4*)(Sm + pb + q * 256);
        Sr[q*4+0] = t.x; Sr[q*4+1] = t.y; Sr[q*4+2] = t.z; Sr[q*4+3] = t.w;
        t = *(const float4*)(bias + pb + q * 256);
        Ar[q*4+0] = t.x; Ar[q*4+1] = t.y; Ar[q*4+2] = t.z; Ar[q*4+3] = t.w;
        int4 p4 = *(const int4*)(Pm + pb + q * 256);
        Pr[q*4+0] = p4.x; Pr[q*4+1] = p4.y; Pr[q*4+2] = p4.z; Pr[q*4+3] = p4.w;
    }

    const int row0 = blockIdx.x * ROWS_PB;
    for (int rr = 0; rr < ROWS_PB; rr++) {
        const int row = row0 + rr;
        const float* xr = x + (size_t)row * NIN;

        // ---- load x, multiply by B (i = q*256 + lane*4 + r)
        float y[16];
        #pragma unroll
        for (int q = 0; q < 4; q++) {
            float4 xv = *(const float4*)(xr + q * 256 + col);
            y[q*4+0] = xv.x * Br[q*4+0];
            y[q*4+1] = xv.y * Br[q*4+1];
            y[q*4+2] = xv.z * Br[q*4+2];
            y[q*4+3] = xv.w * Br[q*4+3];
        }

        fwht1024(y, lane);

        // ---- stage z into LDS in standard order
        #pragma unroll
        for (int q = 0; q < 4; q++) {
            *(float4*)(zbuf + w * NIN + q * 256 + col) =
                make_float4(y[q*4+0], y[q*4+1], y[q*4+2], y[q*4+3]);
        }
        __syncthreads();

        // ---- permutation gather + G scale
        #pragma unroll
        for (int t = 0; t < 16; t++) y[t] = Gr[t] * zbuf[Pr[t]];
        __syncthreads();  // protect zbuf before next row's store

        fwht1024(y, lane);

        // ---- S scale + bias, store
        float* orow = out + (size_t)row * NOUT + w * NIN;
        #pragma unroll
        for (int q = 0; q < 4; q++) {
            float4 ov;
            ov.x = fmaf(Sr[q*4+0], y[q*4+0], Ar[q*4+0]);
            ov.y = fmaf(Sr[q*4+1], y[q*4+1], Ar[q*4+1]);
            ov.z = fmaf(Sr[q*4+2], y[q*4+2], Ar[q*4+2]);
            ov.w = fmaf(Sr[q*4+3], y[q*4+3], Ar[q*4+3]);
            *(float4*)(orow + q * 256 + col) = ov;
        }
    }
}

extern "C" void kernel_launch(void* const* d_in, const int* in_sizes, int n_in,
                              void* d_out, int out_size, void* d_ws, size_t ws_size,
                              hipStream_t stream)
{
    const float* x    = (const float*)d_in[0];
    const float* Bm   = (const float*)d_in[1];
    const float* Gm   = (const float*)d_in[2];
    const float* Sm   = (const float*)d_in[3];
    const float* bias = (const float*)d_in[4];
    const int*   Pm   = (const int*)d_in[5];
    float* out = (float*)d_out;

    hipLaunchKernelGGL(fastfood_kernel, dim3(NBLOCKS), dim3(256), 0, stream,
                       x, Bm, Gm, Sm, bias, Pm, out);
}